// Round 1
// baseline (50077.954 us; speedup 1.0000x reference)
//
#include <hip/hip_runtime.h>
#include <hip/hip_cooperative_groups.h>

namespace cg = cooperative_groups;

// Problem constants
constexpr int kB     = 32;
constexpr int kLAT   = 512;
constexpr int kCH    = 1024;   // conductor hidden
constexpr int kCO    = 512;    // conductor out (emb)
constexpr int kINP   = 389;
constexpr int kH     = 1024;   // decoder hidden
constexpr int kSEQ   = 128;
constexpr int kNSUB  = 8;
constexpr int kSTEPS = 16;
constexpr int kKdec  = 901;    // INP + CO
constexpr int kKdecP = 904;    // padded to /4

#define NBLK 256
#define NTHR 512

// ---------------------------------------------------------------------------
// Persistent device-side state. All activation tensors use the "T4" layout:
//   float index = (k>>2)*128 + b*4 + (k&3)   i.e. (K/4, B=32, 4) fp32
// so a lane owning batch b reads k..k+3 as one float4 at  f4[(k>>2)*32 + b],
// while W rows (contiguous in k) are read as float4 broadcast across b-lanes.
// Everything is (re)initialized every kernel_launch call -> deterministic.
// ---------------------------------------------------------------------------
__device__ __attribute__((aligned(16))) float g_dWih0p[4096 * kKdecP]; // padded dW_ih0
__device__ __attribute__((aligned(16))) float g_lat[kLAT * kB];        // latent, T4
__device__ __attribute__((aligned(16))) float g_xdec[kKdecP * kB];     // [prev | emb | pad], T4
__device__ __attribute__((aligned(16))) float g_hc0[2][kCH * kB];      // conductor h, T4, ping-pong
__device__ __attribute__((aligned(16))) float g_hc1[2][kCH * kB];
__device__ __attribute__((aligned(16))) float g_cc0[kCH * kB];         // conductor c, [j*32+b]
__device__ __attribute__((aligned(16))) float g_cc1[kCH * kB];
__device__ __attribute__((aligned(16))) float g_h0[2][kH * kB];        // decoder h, T4, ping-pong
__device__ __attribute__((aligned(16))) float g_h1[2][kH * kB];
__device__ __attribute__((aligned(16))) float g_c0[kH * kB];           // decoder c, [j*32+b]
__device__ __attribute__((aligned(16))) float g_c1[kH * kB];

__device__ __forceinline__ float fast_sig(float x) {
  return 1.0f / (1.0f + __expf(-x));
}
__device__ __forceinline__ float fast_tanh(float x) {
  // well-behaved at +-inf: exp(2x)->inf => 1, exp(2x)->0 => -1
  return 1.0f - 2.0f / (__expf(2.0f * x) + 1.0f);
}

// dot over K (nq float4 quads) between one W row and activation xT4 for batch b
__device__ __forceinline__ float dotq(const float* __restrict__ Wrow,
                                      const float* __restrict__ xT4,
                                      int nq, int b) {
  const float4* __restrict__ W4 = (const float4*)Wrow;
  const float4* __restrict__ X4 = (const float4*)xT4;
  float a0 = 0.f, a1 = 0.f, a2 = 0.f, a3 = 0.f;
#pragma unroll 8
  for (int q = 0; q < nq; ++q) {
    float4 w = W4[q];
    float4 x = X4[(q << 5) + b];
    a0 = fmaf(w.x, x.x, a0);
    a1 = fmaf(w.y, x.y, a1);
    a2 = fmaf(w.z, x.z, a2);
    a3 = fmaf(w.w, x.w, a3);
  }
  return (a0 + a1) + (a2 + a3);
}

struct KParams {
  const float* hdi;  const float* cdi;
  const float* cWih0; const float* cWhh0; const float* cb0;
  const float* cWih1; const float* cWhh1; const float* cb1;
  const float* cOutW; const float* cOutb;
  const float* dWhh0; const float* db0;
  const float* dWih1; const float* dWhh1; const float* db1;
  const float* dOutW; const float* dOutb;
  float* out;
};

// gate exchange buffer: gbuf[gate*4 + j_local][b]
__device__ __forceinline__ void gate_update(float (&gbuf)[16][32], int tid,
                                            float* __restrict__ cbuf,
                                            float* __restrict__ hT4out) {
  __syncthreads();
  if (tid < 128) {
    int bb = tid & 31;
    int jj = tid >> 5;                    // j_local 0..3
    float gi = gbuf[jj][bb];
    float gf = gbuf[4 + jj][bb];
    float gg = gbuf[8 + jj][bb];
    float go = gbuf[12 + jj][bb];
    int jg = (blockIdx.x << 2) + jj;      // global j
    float c  = cbuf[(jg << 5) + bb];
    float iv = fast_sig(gi);
    float fv = fast_sig(gf);
    float gv = fast_tanh(gg);
    float ov = fast_sig(go);
    float cn = fmaf(fv, c, iv * gv);
    float hn = ov * fast_tanh(cn);
    cbuf[(jg << 5) + bb] = cn;
    hT4out[((jg >> 2) << 7) + (bb << 2) + (jg & 3)] = hn;
  }
}

__global__ __launch_bounds__(NTHR, 2) void decoder_persistent(KParams P) {
  cg::grid_group grid = cg::this_grid();
  const int tid   = threadIdx.x;
  const int b     = tid & 31;
  const int row16 = tid >> 5;             // 0..15 : gate*4 + j_local
  const int g     = row16 >> 2;
  const int jl    = row16 & 3;
  const int j     = (blockIdx.x << 2) + jl;
  const int grow  = (g << 10) + j;        // row in (4096, K) weight
  const int gid   = blockIdx.x * NTHR + tid;

  __shared__ float gbuf[16][32];

  for (int s = 0; s < kNSUB; ++s) {
    const int p = s & 1;

    // ---- conductor layer 0: x = latent (K=512) ----
    {
      float acc = dotq(P.cWih0 + (size_t)grow * kLAT, g_lat, kLAT / 4, b)
                + dotq(P.cWhh0 + (size_t)grow * kCH, g_hc0[p], kCH / 4, b)
                + P.cb0[grow];
      gbuf[row16][b] = acc;
      gate_update(gbuf, tid, g_cc0, g_hc0[p ^ 1]);
    }
    grid.sync();

    // ---- conductor layer 1: x = hc0_new (K=1024) ----
    {
      float acc = dotq(P.cWih1 + (size_t)grow * kCH, g_hc0[p ^ 1], kCH / 4, b)
                + dotq(P.cWhh1 + (size_t)grow * kCH, g_hc1[p], kCH / 4, b)
                + P.cb1[grow];
      gbuf[row16][b] = acc;
      gate_update(gbuf, tid, g_cc1, g_hc1[p ^ 1]);
    }
    grid.sync();

    // ---- emb = tanh(hc1 @ cOutW.T + b) into xdec[389..901)
    //      + copy this subsequence's decoder init states ----
    {
      // decoder state init: 4 * 32768 copy tasks, one per lane
      int which = gid >> 15;               // 0:h0 1:c0 2:h1 3:c1
      int idx   = gid & 32767;
      int jj2   = idx & 1023;
      int bb2   = idx >> 10;
      const float* src = (which & 1) ? P.cdi : P.hdi;
      int L = which >> 1;
      float v = src[(((size_t)(s * 2 + L)) * 32 + bb2) * 1024 + jj2];
      if (which & 1) {
        float* dst = (which == 1) ? g_c0 : g_c1;
        dst[(jj2 << 5) + bb2] = v;
      } else {
        float* dst = (which == 0) ? g_h0[0] : g_h1[0];
        dst[((jj2 >> 2) << 7) + (bb2 << 2) + (jj2 & 3)] = v;
      }
      if (gid < kB * kCO) {
        int b2 = gid & 31, i = gid >> 5;
        float e = dotq(P.cOutW + (size_t)i * kCH, g_hc1[p ^ 1], kCH / 4, b2)
                + P.cOutb[i];
        e = fast_tanh(e);
        int k = kINP + i;
        g_xdec[((k >> 2) << 7) + (b2 << 2) + (k & 3)] = e;
      }
    }
    grid.sync();

    for (int t = 0; t < kSTEPS; ++t) {
      const int q = t & 1;

      // ---- decoder layer 0: x = [prev|emb] (K=904 padded) ----
      {
        float acc = dotq(g_dWih0p + (size_t)grow * kKdecP, g_xdec, kKdecP / 4, b)
                  + dotq(P.dWhh0 + (size_t)grow * kH, g_h0[q], kH / 4, b)
                  + P.db0[grow];
        gbuf[row16][b] = acc;
        gate_update(gbuf, tid, g_c0, g_h0[q ^ 1]);
      }
      grid.sync();

      // ---- decoder layer 1: x = h0_new (K=1024) ----
      {
        float acc = dotq(P.dWih1 + (size_t)grow * kH, g_h0[q ^ 1], kH / 4, b)
                  + dotq(P.dWhh1 + (size_t)grow * kH, g_h1[q], kH / 4, b)
                  + P.db1[grow];
        gbuf[row16][b] = acc;
        gate_update(gbuf, tid, g_c1, g_h1[q ^ 1]);
      }
      grid.sync();

      // ---- output projection: prev = tanh(h1 @ dOutW.T + b) ----
      if (gid < kB * kINP) {
        int b2 = gid & 31, i = gid >> 5;
        float v = dotq(P.dOutW + (size_t)i * kH, g_h1[q ^ 1], kH / 4, b2)
                + P.dOutb[i];
        v = fast_tanh(v);
        g_xdec[((i >> 2) << 7) + (b2 << 2) + (i & 3)] = v;
        P.out[(size_t)b2 * (kSEQ * kINP) + (size_t)(s * kSTEPS + t) * kINP + i] = v;
      }
      grid.sync();
    }
  }
}

// ---------------------------------------------------------------------------
// Prep: zero state, pack latent into T4, pad dW_ih0 (901 -> 904 cols, zeros).
// Runs every call (deterministic; no state carried across calls).
// ---------------------------------------------------------------------------
__global__ void prep_kernel(const float* __restrict__ latent,
                            const float* __restrict__ dWih0) {
  size_t i0 = (size_t)blockIdx.x * blockDim.x + threadIdx.x;
  size_t stride = (size_t)gridDim.x * blockDim.x;

  for (size_t k = i0; k < (size_t)kKdecP * kB; k += stride) g_xdec[k] = 0.f;
  for (size_t k = i0; k < (size_t)kCH * kB; k += stride) {
    g_hc0[0][k] = 0.f;
    g_hc1[0][k] = 0.f;
    g_cc0[k]    = 0.f;
    g_cc1[k]    = 0.f;
  }
  for (size_t idx = i0; idx < (size_t)kLAT * kB; idx += stride) {
    int k  = (int)(idx & (kLAT - 1));
    int bb = (int)(idx >> 9);
    g_lat[((k >> 2) << 7) + (bb << 2) + (k & 3)] = latent[(size_t)bb * kLAT + k];
  }
  for (size_t idx = i0; idx < (size_t)4096 * kKdecP; idx += stride) {
    int r = (int)(idx / kKdecP);
    int k = (int)(idx % kKdecP);
    g_dWih0p[idx] = (k < kKdec) ? dWih0[(size_t)r * kKdec + k] : 0.f;
  }
}

extern "C" void kernel_launch(void* const* d_in, const int* in_sizes, int n_in,
                              void* d_out, int out_size, void* d_ws, size_t ws_size,
                              hipStream_t stream) {
  const float* latent = (const float*)d_in[0];
  // d_in[1] = target (int64) -- unused (teacher forcing off in reference)
  const float* hdi   = (const float*)d_in[2];
  const float* cdi   = (const float*)d_in[3];
  const float* cWih0 = (const float*)d_in[4];
  const float* cWhh0 = (const float*)d_in[5];
  const float* cb0   = (const float*)d_in[6];
  const float* cWih1 = (const float*)d_in[7];
  const float* cWhh1 = (const float*)d_in[8];
  const float* cb1   = (const float*)d_in[9];
  const float* cOutW = (const float*)d_in[10];
  const float* cOutb = (const float*)d_in[11];
  const float* dWih0 = (const float*)d_in[12];
  const float* dWhh0 = (const float*)d_in[13];
  const float* db0   = (const float*)d_in[14];
  const float* dWih1 = (const float*)d_in[15];
  const float* dWhh1 = (const float*)d_in[16];
  const float* db1   = (const float*)d_in[17];
  const float* dOutW = (const float*)d_in[18];
  const float* dOutb = (const float*)d_in[19];
  float* out = (float*)d_out;

  hipLaunchKernelGGL(prep_kernel, dim3(1024), dim3(256), 0, stream, latent, dWih0);

  KParams hp;
  hp.hdi = hdi;     hp.cdi = cdi;
  hp.cWih0 = cWih0; hp.cWhh0 = cWhh0; hp.cb0 = cb0;
  hp.cWih1 = cWih1; hp.cWhh1 = cWhh1; hp.cb1 = cb1;
  hp.cOutW = cOutW; hp.cOutb = cOutb;
  hp.dWhh0 = dWhh0; hp.db0 = db0;
  hp.dWih1 = dWih1; hp.dWhh1 = dWhh1; hp.db1 = db1;
  hp.dOutW = dOutW; hp.dOutb = dOutb;
  hp.out = out;

  void* args[] = { &hp };
  hipLaunchCooperativeKernel((void*)decoder_persistent, dim3(NBLK), dim3(NTHR),
                             args, 0, stream);
}

// Round 2
// 29831.860 us; speedup vs baseline: 1.6787x; 1.6787x over previous
//
#include <hip/hip_runtime.h>
#include <hip/hip_cooperative_groups.h>

namespace cg = cooperative_groups;

// Problem constants
constexpr int kB     = 32;
constexpr int kLAT   = 512;
constexpr int kCH    = 1024;   // conductor hidden
constexpr int kCO    = 512;    // conductor out (emb)
constexpr int kINP   = 389;
constexpr int kH     = 1024;   // decoder hidden
constexpr int kSEQ   = 128;
constexpr int kNSUB  = 8;
constexpr int kSTEPS = 16;
constexpr int kKdec  = 901;    // INP + CO
constexpr int kKdecP = 928;    // padded so quad count (232) is divisible by 4

#define NBLK 256
#define NTHR 1024

// ---------------------------------------------------------------------------
// T4 layout for activations: float index = (k>>2)*128 + b*4 + (k&3)
//   -> lane owning batch b reads quad q as float4 at  f4[q*32 + b]
// Weight rows are contiguous fp32, read as float4 (broadcast across b-lanes).
// ---------------------------------------------------------------------------
__device__ __attribute__((aligned(16))) float g_dWih0p[4096 * kKdecP]; // padded dW_ih0
__device__ __attribute__((aligned(16))) float g_lat[kLAT * kB];        // latent, T4
__device__ __attribute__((aligned(16))) float g_xdec[kKdecP * kB];     // [prev | emb | pad], T4
__device__ __attribute__((aligned(16))) float g_hc0[2][kCH * kB];      // conductor h, T4, ping-pong
__device__ __attribute__((aligned(16))) float g_hc1[2][kCH * kB];
__device__ __attribute__((aligned(16))) float g_cc0[kCH * kB];         // conductor c, [j*32+b]
__device__ __attribute__((aligned(16))) float g_cc1[kCH * kB];
__device__ __attribute__((aligned(16))) float g_h0[2][kH * kB];        // decoder h, T4, ping-pong
__device__ __attribute__((aligned(16))) float g_h1[2][kH * kB];
__device__ __attribute__((aligned(16))) float g_c0[kH * kB];           // decoder c, [j*32+b]
__device__ __attribute__((aligned(16))) float g_c1[kH * kB];

__device__ __forceinline__ float fast_sig(float x) {
  return 1.0f / (1.0f + __expf(-x));
}
__device__ __forceinline__ float fast_tanh(float x) {
  return 1.0f - 2.0f / (__expf(2.0f * x) + 1.0f);
}

// ---------------------------------------------------------------------------
// Software-pipelined dot: nq quads (nq % 4 == 0), double-buffered chunks of 4.
// Keeps ~8 16B loads in flight per lane while 16 FMAs retire.
// X4 is pre-offset by batch b; x quad q lives at X4[q*32].
// ---------------------------------------------------------------------------
__device__ __forceinline__ float dotq_pipe(const float4* __restrict__ W4,
                                           const float4* __restrict__ X4,
                                           int nq) {
  float a0 = 0.f, a1 = 0.f, a2 = 0.f, a3 = 0.f;
  const int nc = nq >> 2;
  float4 wa0 = W4[0], wa1 = W4[1], wa2 = W4[2], wa3 = W4[3];
  float4 xa0 = X4[0], xa1 = X4[32], xa2 = X4[64], xa3 = X4[96];
  for (int c = 1; c < nc; ++c) {
    const float4* Wn = W4 + (c << 2);
    const float4* Xn = X4 + (c << 7);
    float4 wb0 = Wn[0], wb1 = Wn[1], wb2 = Wn[2], wb3 = Wn[3];
    float4 xb0 = Xn[0], xb1 = Xn[32], xb2 = Xn[64], xb3 = Xn[96];
    a0 = fmaf(wa0.x, xa0.x, a0); a1 = fmaf(wa0.y, xa0.y, a1);
    a2 = fmaf(wa0.z, xa0.z, a2); a3 = fmaf(wa0.w, xa0.w, a3);
    a0 = fmaf(wa1.x, xa1.x, a0); a1 = fmaf(wa1.y, xa1.y, a1);
    a2 = fmaf(wa1.z, xa1.z, a2); a3 = fmaf(wa1.w, xa1.w, a3);
    a0 = fmaf(wa2.x, xa2.x, a0); a1 = fmaf(wa2.y, xa2.y, a1);
    a2 = fmaf(wa2.z, xa2.z, a2); a3 = fmaf(wa2.w, xa2.w, a3);
    a0 = fmaf(wa3.x, xa3.x, a0); a1 = fmaf(wa3.y, xa3.y, a1);
    a2 = fmaf(wa3.z, xa3.z, a2); a3 = fmaf(wa3.w, xa3.w, a3);
    wa0 = wb0; wa1 = wb1; wa2 = wb2; wa3 = wb3;
    xa0 = xb0; xa1 = xb1; xa2 = xb2; xa3 = xb3;
  }
  a0 = fmaf(wa0.x, xa0.x, a0); a1 = fmaf(wa0.y, xa0.y, a1);
  a2 = fmaf(wa0.z, xa0.z, a2); a3 = fmaf(wa0.w, xa0.w, a3);
  a0 = fmaf(wa1.x, xa1.x, a0); a1 = fmaf(wa1.y, xa1.y, a1);
  a2 = fmaf(wa1.z, xa1.z, a2); a3 = fmaf(wa1.w, xa1.w, a3);
  a0 = fmaf(wa2.x, xa2.x, a0); a1 = fmaf(wa2.y, xa2.y, a1);
  a2 = fmaf(wa2.z, xa2.z, a2); a3 = fmaf(wa2.w, xa2.w, a3);
  a0 = fmaf(wa3.x, xa3.x, a0); a1 = fmaf(wa3.y, xa3.y, a1);
  a2 = fmaf(wa3.z, xa3.z, a2); a3 = fmaf(wa3.w, xa3.w, a3);
  return (a0 + a1) + (a2 + a3);
}

// 16-quad dot for the K/16-split projection phases
__device__ __forceinline__ float dot16(const float4* __restrict__ W4,
                                       const float4* __restrict__ X4) {
  float a0 = 0.f, a1 = 0.f, a2 = 0.f, a3 = 0.f;
#pragma unroll
  for (int q = 0; q < 16; ++q) {
    float4 w = W4[q];
    float4 x = X4[q << 5];
    a0 = fmaf(w.x, x.x, a0); a1 = fmaf(w.y, x.y, a1);
    a2 = fmaf(w.z, x.z, a2); a3 = fmaf(w.w, x.w, a3);
  }
  return (a0 + a1) + (a2 + a3);
}

struct KParams {
  const float* hdi;  const float* cdi;
  const float* cWih0; const float* cWhh0; const float* cb0;
  const float* cWih1; const float* cWhh1; const float* cb1;
  const float* cOutW; const float* cOutb;
  const float* dWhh0; const float* db0;
  const float* dWih1; const float* dWhh1; const float* db1;
  const float* dOutW; const float* dOutb;
  float* out;
};

// gate exchange buffer: gbuf[khalf][gate*4 + j_local][b]; both K-halves summed
__device__ __forceinline__ void gate_update(float (&gbuf)[2][16][32], int tid,
                                            float* __restrict__ cbuf,
                                            float* __restrict__ hT4out) {
  __syncthreads();
  if (tid < 128) {
    int bb = tid & 31;
    int jj = tid >> 5;                    // j_local 0..3
    float gi = gbuf[0][jj][bb]      + gbuf[1][jj][bb];
    float gf = gbuf[0][4 + jj][bb]  + gbuf[1][4 + jj][bb];
    float gg = gbuf[0][8 + jj][bb]  + gbuf[1][8 + jj][bb];
    float go = gbuf[0][12 + jj][bb] + gbuf[1][12 + jj][bb];
    int jg = (blockIdx.x << 2) + jj;      // global j
    float c  = cbuf[(jg << 5) + bb];
    float iv = fast_sig(gi);
    float fv = fast_sig(gf);
    float gv = fast_tanh(gg);
    float ov = fast_sig(go);
    float cn = fmaf(fv, c, iv * gv);
    float hn = ov * fast_tanh(cn);
    cbuf[(jg << 5) + bb] = cn;
    hT4out[((jg >> 2) << 7) + (bb << 2) + (jg & 3)] = hn;
  }
}

__global__ __launch_bounds__(NTHR, 4) void decoder_persistent(KParams P) {
  cg::grid_group grid = cg::this_grid();
  const int tid   = threadIdx.x;
  const int khalf = tid >> 9;             // 0: W_ih*x side, 1: W_hh*h side
  const int low   = tid & 511;
  const int b     = low & 31;
  const int row16 = low >> 5;             // 0..15 : gate*4 + j_local
  const int g     = row16 >> 2;
  const int jl    = row16 & 3;
  const int j     = (blockIdx.x << 2) + jl;
  const int grow  = (g << 10) + j;        // row in (4096, K) weight
  const int gid   = blockIdx.x * NTHR + tid;
  // projection-phase mapping: 16 lanes per dot, contiguous ksub
  const int pd    = blockIdx.x * 64 + (tid >> 4);  // dot index 0..16383
  const int ksub  = tid & 15;

  __shared__ float gbuf[2][16][32];

  for (int s = 0; s < kNSUB; ++s) {
    const int p = s & 1;

    // ---- conductor layer 0: x = latent (K=512) ----
    {
      float acc;
      if (khalf == 0)
        acc = dotq_pipe((const float4*)(P.cWih0 + (size_t)grow * kLAT),
                        (const float4*)g_lat + b, kLAT / 4) + P.cb0[grow];
      else
        acc = dotq_pipe((const float4*)(P.cWhh0 + (size_t)grow * kCH),
                        (const float4*)g_hc0[p] + b, kCH / 4);
      gbuf[khalf][row16][b] = acc;
      gate_update(gbuf, tid, g_cc0, g_hc0[p ^ 1]);
    }
    grid.sync();

    // ---- conductor layer 1: x = hc0_new (K=1024) ----
    {
      float acc;
      if (khalf == 0)
        acc = dotq_pipe((const float4*)(P.cWih1 + (size_t)grow * kCH),
                        (const float4*)g_hc0[p ^ 1] + b, kCH / 4) + P.cb1[grow];
      else
        acc = dotq_pipe((const float4*)(P.cWhh1 + (size_t)grow * kCH),
                        (const float4*)g_hc1[p] + b, kCH / 4);
      gbuf[khalf][row16][b] = acc;
      gate_update(gbuf, tid, g_cc1, g_hc1[p ^ 1]);
    }
    grid.sync();

    // ---- emb = tanh(hc1 @ cOutW.T + b), 16-way K-split
    //      + copy this subsequence's decoder init states ----
    {
      if (gid < 131072) {
        int which = gid >> 15;             // 0:h0 1:c0 2:h1 3:c1
        int idx   = gid & 32767;
        int jj2   = idx & 1023;
        int bb2   = idx >> 10;
        const float* src = (which & 1) ? P.cdi : P.hdi;
        int L = which >> 1;
        float v = src[(((size_t)(s * 2 + L)) * 32 + bb2) * 1024 + jj2];
        if (which & 1) {
          float* dst = (which == 1) ? g_c0 : g_c1;
          dst[(jj2 << 5) + bb2] = v;
        } else {
          float* dst = (which == 0) ? g_h0[0] : g_h1[0];
          dst[((jj2 >> 2) << 7) + (bb2 << 2) + (jj2 & 3)] = v;
        }
      }
      int b2 = pd & 31, i = pd >> 5;       // all pd < 16384 valid (32*512)
      float v = dot16((const float4*)(P.cOutW + (size_t)i * kCH) + (ksub << 4),
                      (const float4*)g_hc1[p ^ 1] + (ksub << 9) + b2);
      v += __shfl_xor(v, 1); v += __shfl_xor(v, 2);
      v += __shfl_xor(v, 4); v += __shfl_xor(v, 8);
      if (ksub == 0) {
        float e = fast_tanh(v + P.cOutb[i]);
        int k = kINP + i;
        g_xdec[((k >> 2) << 7) + (b2 << 2) + (k & 3)] = e;
      }
    }
    grid.sync();

    for (int t = 0; t < kSTEPS; ++t) {
      const int q = t & 1;

      // ---- decoder layer 0: x = [prev|emb] (K=928 padded) ----
      {
        float acc;
        if (khalf == 0)
          acc = dotq_pipe((const float4*)(g_dWih0p + (size_t)grow * kKdecP),
                          (const float4*)g_xdec + b, kKdecP / 4) + P.db0[grow];
        else
          acc = dotq_pipe((const float4*)(P.dWhh0 + (size_t)grow * kH),
                          (const float4*)g_h0[q] + b, kH / 4);
        gbuf[khalf][row16][b] = acc;
        gate_update(gbuf, tid, g_c0, g_h0[q ^ 1]);
      }
      grid.sync();

      // ---- decoder layer 1: x = h0_new (K=1024) ----
      {
        float acc;
        if (khalf == 0)
          acc = dotq_pipe((const float4*)(P.dWih1 + (size_t)grow * kH),
                          (const float4*)g_h0[q ^ 1] + b, kH / 4) + P.db1[grow];
        else
          acc = dotq_pipe((const float4*)(P.dWhh1 + (size_t)grow * kH),
                          (const float4*)g_h1[q] + b, kH / 4);
        gbuf[khalf][row16][b] = acc;
        gate_update(gbuf, tid, g_c1, g_h1[q ^ 1]);
      }
      grid.sync();

      // ---- output projection: prev = tanh(h1 @ dOutW.T + b), 16-way split ----
      {
        int b2 = pd & 31, i = pd >> 5;
        bool valid = pd < kB * kINP;       // 12448
        float v = 0.f;
        if (valid)
          v = dot16((const float4*)(P.dOutW + (size_t)i * kH) + (ksub << 4),
                    (const float4*)g_h1[q ^ 1] + (ksub << 9) + b2);
        v += __shfl_xor(v, 1); v += __shfl_xor(v, 2);
        v += __shfl_xor(v, 4); v += __shfl_xor(v, 8);
        if (valid && ksub == 0) {
          float o = fast_tanh(v + P.dOutb[i]);
          g_xdec[((i >> 2) << 7) + (b2 << 2) + (i & 3)] = o;
          P.out[(size_t)b2 * (kSEQ * kINP) + (size_t)(s * kSTEPS + t) * kINP + i] = o;
        }
      }
      grid.sync();
    }
  }
}

// ---------------------------------------------------------------------------
// Prep: zero state, pack latent into T4, pad dW_ih0 (901 -> 928 cols, zeros).
// ---------------------------------------------------------------------------
__global__ void prep_kernel(const float* __restrict__ latent,
                            const float* __restrict__ dWih0) {
  size_t i0 = (size_t)blockIdx.x * blockDim.x + threadIdx.x;
  size_t stride = (size_t)gridDim.x * blockDim.x;

  for (size_t k = i0; k < (size_t)kKdecP * kB; k += stride) g_xdec[k] = 0.f;
  for (size_t k = i0; k < (size_t)kCH * kB; k += stride) {
    g_hc0[0][k] = 0.f;
    g_hc1[0][k] = 0.f;
    g_cc0[k]    = 0.f;
    g_cc1[k]    = 0.f;
  }
  for (size_t idx = i0; idx < (size_t)kLAT * kB; idx += stride) {
    int k  = (int)(idx & (kLAT - 1));
    int bb = (int)(idx >> 9);
    g_lat[((k >> 2) << 7) + (bb << 2) + (k & 3)] = latent[(size_t)bb * kLAT + k];
  }
  for (size_t idx = i0; idx < (size_t)4096 * kKdecP; idx += stride) {
    int r = (int)(idx / kKdecP);
    int k = (int)(idx % kKdecP);
    g_dWih0p[idx] = (k < kKdec) ? dWih0[(size_t)r * kKdec + k] : 0.f;
  }
}

extern "C" void kernel_launch(void* const* d_in, const int* in_sizes, int n_in,
                              void* d_out, int out_size, void* d_ws, size_t ws_size,
                              hipStream_t stream) {
  const float* latent = (const float*)d_in[0];
  // d_in[1] = target (int64) -- unused (teacher forcing off in reference)
  const float* hdi   = (const float*)d_in[2];
  const float* cdi   = (const float*)d_in[3];
  const float* cWih0 = (const float*)d_in[4];
  const float* cWhh0 = (const float*)d_in[5];
  const float* cb0   = (const float*)d_in[6];
  const float* cWih1 = (const float*)d_in[7];
  const float* cWhh1 = (const float*)d_in[8];
  const float* cb1   = (const float*)d_in[9];
  const float* cOutW = (const float*)d_in[10];
  const float* cOutb = (const float*)d_in[11];
  const float* dWih0 = (const float*)d_in[12];
  const float* dWhh0 = (const float*)d_in[13];
  const float* db0   = (const float*)d_in[14];
  const float* dWih1 = (const float*)d_in[15];
  const float* dWhh1 = (const float*)d_in[16];
  const float* db1   = (const float*)d_in[17];
  const float* dOutW = (const float*)d_in[18];
  const float* dOutb = (const float*)d_in[19];
  float* out = (float*)d_out;

  hipLaunchKernelGGL(prep_kernel, dim3(1024), dim3(256), 0, stream, latent, dWih0);

  KParams hp;
  hp.hdi = hdi;     hp.cdi = cdi;
  hp.cWih0 = cWih0; hp.cWhh0 = cWhh0; hp.cb0 = cb0;
  hp.cWih1 = cWih1; hp.cWhh1 = cWhh1; hp.cb1 = cb1;
  hp.cOutW = cOutW; hp.cOutb = cOutb;
  hp.dWhh0 = dWhh0; hp.db0 = db0;
  hp.dWih1 = dWih1; hp.dWhh1 = dWhh1; hp.db1 = db1;
  hp.dOutW = dOutW; hp.dOutb = dOutb;
  hp.out = out;

  void* args[] = { &hp };
  hipLaunchCooperativeKernel((void*)decoder_persistent, dim3(NBLK), dim3(NTHR),
                             args, 0, stream);
}